// Round 3
// baseline (1732.916 us; speedup 1.0000x reference)
//
#include <hip/hip_runtime.h>
#include <hip/hip_bf16.h>
#include <stdint.h>

typedef __bf16 bf16x8_t __attribute__((ext_vector_type(8)));
typedef float  f32x4_t  __attribute__((ext_vector_type(4)));

// async global->LDS, 16B per lane. LDS dest must be wave-uniform base + lane*16.
__device__ __forceinline__ void gld_lds16(const void* g, void* l) {
    __builtin_amdgcn_global_load_lds(
        (const __attribute__((address_space(1))) uint32_t*)g,
        (__attribute__((address_space(3))) uint32_t*)l, 16, 0, 0);
}

// ---------------------------------------------------------------- conv1 (fp32 vector)
// x[16,100,64,1] -> y[16,92,56,256] bf16, relu. block=(b,oh), thread=oc.
__global__ __launch_bounds__(256) void k_conv1(
    const float* __restrict__ x, const float* __restrict__ w,
    const float* __restrict__ bias, __hip_bfloat16* __restrict__ y)
{
    const int b  = blockIdx.x / 92;
    const int oh = blockIdx.x % 92;
    const int oc = threadIdx.x;
    float wr[81];
#pragma unroll
    for (int t = 0; t < 81; ++t) wr[t] = w[t * 256 + oc];
    const float bs = bias[oc];
    const float* xb = x + (b * 100 + oh) * 64;
    __hip_bfloat16* yb = y + ((b * 92 + oh) * 56) * 256 + oc;
    for (int owg = 0; owg < 56; owg += 4) {
        float a0 = bs, a1 = bs, a2 = bs, a3 = bs;
#pragma unroll
        for (int kh = 0; kh < 9; ++kh) {
            const float* xr = xb + kh * 64 + owg;   // uniform -> s_load
            float xv[12];
#pragma unroll
            for (int t = 0; t < 12; ++t) xv[t] = xr[t];
#pragma unroll
            for (int kw = 0; kw < 9; ++kw) {
                const float wv = wr[kh * 9 + kw];
                a0 = fmaf(xv[kw + 0], wv, a0);
                a1 = fmaf(xv[kw + 1], wv, a1);
                a2 = fmaf(xv[kw + 2], wv, a2);
                a3 = fmaf(xv[kw + 3], wv, a3);
            }
        }
        yb[(owg + 0) * 256] = __float2bfloat16(fmaxf(a0, 0.f));
        yb[(owg + 1) * 256] = __float2bfloat16(fmaxf(a1, 0.f));
        yb[(owg + 2) * 256] = __float2bfloat16(fmaxf(a2, 0.f));
        yb[(owg + 3) * 256] = __float2bfloat16(fmaxf(a3, 0.f));
    }
}

// ---------------------------------------------------------------- pc_w transpose+cast
__global__ __launch_bounds__(256) void k_wt(
    const float* __restrict__ w, __hip_bfloat16* __restrict__ wt)
{
    const int idx = blockIdx.x * 256 + threadIdx.x;   // < 256*20736
    const int oc  = idx / 20736;
    const int k   = idx - oc * 20736;
    wt[idx] = __float2bfloat16(w[k * 256 + oc]);
}

// ---------------------------------------------------------------- PC conv as MFMA GEMM
// M=16128 (b,oh,ow), N=256 (oc), K=20736. 128x128 tile, BK=32, K-split x3.
__global__ __launch_bounds__(256) void k_pcconv(
    const __hip_bfloat16* __restrict__ y,
    const __hip_bfloat16* __restrict__ wt,
    float* __restrict__ pout0, float* __restrict__ pout1, float* __restrict__ pout2)
{
    __shared__ __hip_bfloat16 lA[128 * 32];
    __shared__ __hip_bfloat16 lB[128 * 32];
    float* __restrict__ p = (blockIdx.z == 0) ? pout0 : (blockIdx.z == 1 ? pout1 : pout2);

    const int tid  = threadIdx.x;
    const int m0   = blockIdx.x * 128;
    const int n0   = blockIdx.y * 128;
    const int kc0  = blockIdx.z * 216;
    const int quad = tid & 3;
    const int trow = tid >> 2;

    int ybase[2];
#pragma unroll
    for (int r = 0; r < 2; ++r) {
        const int m  = m0 + r * 64 + trow;
        const int b  = m / 1008;            // 42*24
        const int rm = m - b * 1008;
        const int oh = rm / 24;
        const int ow = rm - oh * 24;
        ybase[r] = ((b * 92 + 2 * oh) * 56 + 2 * ow) * 256 + quad * 8;
    }
    int wbase[2];
#pragma unroll
    for (int r = 0; r < 2; ++r)
        wbase[r] = (n0 + r * 64 + trow) * 20736 + quad * 8;

    f32x4_t acc[4][4];
#pragma unroll
    for (int mi = 0; mi < 4; ++mi)
#pragma unroll
        for (int ni = 0; ni < 4; ++ni)
            acc[mi][ni] = (f32x4_t){0.f, 0.f, 0.f, 0.f};

    const int wv   = tid >> 6;
    const int lane = tid & 63;
    const int mw   = (wv >> 1) * 64;
    const int nw   = (wv & 1) * 64;
    const int lr   = lane & 15;
    const int lq   = lane >> 4;

    for (int kc = kc0; kc < kc0 + 216; ++kc) {
        const int k0   = kc * 32;
        const int khw  = k0 >> 8;
        const int ic0  = k0 & 255;
        const int kh   = khw / 9;
        const int kw2  = khw - kh * 9;
        const int aoff = (kh * 56 + kw2) * 256 + ic0;
        __syncthreads();
#pragma unroll
        for (int r = 0; r < 2; ++r)
            gld_lds16(y + ybase[r] + aoff, &lA[r * 2048 + tid * 8]);
#pragma unroll
        for (int r = 0; r < 2; ++r)
            gld_lds16(wt + wbase[r] + k0, &lB[r * 2048 + tid * 8]);
        __builtin_amdgcn_s_waitcnt(0);
        __syncthreads();
        bf16x8_t af[4], bfr[4];
#pragma unroll
        for (int mi = 0; mi < 4; ++mi)
            af[mi] = *(const bf16x8_t*)&lA[(mw + mi * 16 + lr) * 32 + lq * 8];
#pragma unroll
        for (int ni = 0; ni < 4; ++ni)
            bfr[ni] = *(const bf16x8_t*)&lB[(nw + ni * 16 + lr) * 32 + lq * 8];
#pragma unroll
        for (int mi = 0; mi < 4; ++mi)
#pragma unroll
            for (int ni = 0; ni < 4; ++ni)
                acc[mi][ni] = __builtin_amdgcn_mfma_f32_16x16x32_bf16(
                    af[mi], bfr[ni], acc[mi][ni], 0, 0, 0);
    }
#pragma unroll
    for (int mi = 0; mi < 4; ++mi)
#pragma unroll
        for (int ni = 0; ni < 4; ++ni) {
            const int col = n0 + nw + ni * 16 + lr;
#pragma unroll
            for (int rr = 0; rr < 4; ++rr) {
                const int row = m0 + mw + mi * 16 + lq * 4 + rr;
                p[row * 256 + col] = acc[mi][ni][rr];
            }
        }
}

// ---------------------------------------------------------------- squash (sums K-splits)
__global__ __launch_bounds__(256) void k_squash(
    const float* p0, const float* p1, const float* p2,
    const float* __restrict__ bias, float* u)
{
    const int g = blockIdx.x * 256 + threadIdx.x;   // < 516096
    const int base = g * 8;
    const int cb = (g & 31) * 8;
    float v[8]; float sq = 0.f;
    const float4 a0 = *(const float4*)(p0 + base), a1 = *(const float4*)(p0 + base + 4);
    const float4 b0 = *(const float4*)(p1 + base), b1 = *(const float4*)(p1 + base + 4);
    const float4 c0 = *(const float4*)(p2 + base), c1 = *(const float4*)(p2 + base + 4);
    v[0] = a0.x + b0.x + c0.x + bias[cb + 0];
    v[1] = a0.y + b0.y + c0.y + bias[cb + 1];
    v[2] = a0.z + b0.z + c0.z + bias[cb + 2];
    v[3] = a0.w + b0.w + c0.w + bias[cb + 3];
    v[4] = a1.x + b1.x + c1.x + bias[cb + 4];
    v[5] = a1.y + b1.y + c1.y + bias[cb + 5];
    v[6] = a1.z + b1.z + c1.z + bias[cb + 6];
    v[7] = a1.w + b1.w + c1.w + bias[cb + 7];
#pragma unroll
    for (int t = 0; t < 8; ++t) sq += v[t] * v[t];
    const float sc = sq / ((1.f + sq) * sqrtf(sq + 1e-7f));
#pragma unroll
    for (int t = 0; t < 8; ++t) u[base + t] = v[t] * sc;
}

// ---------------------------------------------------------------- routing iteration (direct)
// One W pass per iteration, all math in registers. Thread = one (i, q):
// lane q owns output dims [4q, 4q+4). blockIdx.x = b (fastest-varying -> the 16
// blocks sharing a W chunk are dispatched back-to-back, L2/L3 broadcasts the
// 16x batch duplication). blockIdx.y = i-chunk of 64 capsules.
// logit_j = vsum_bj . uh_bij (vsum = sum of previous v; zero on iter 0 ->
// softmax = exactly 0.1, matching the reference's b=0 start).
__global__ __launch_bounds__(256) void k_route3(
    const float* __restrict__ u, const float* __restrict__ W,
    const float* __restrict__ vsum, float* __restrict__ sp)
{
    __shared__ float red[4 * 160];
    const int b    = blockIdx.x;
    const int tid  = threadIdx.x;
    const int lane = tid & 63;
    const int wv   = tid >> 6;
    const int q    = tid & 3;
    const int i    = blockIdx.y * 64 + (tid >> 2);

    // u[b,i,0..8)
    const float* up = u + (b * 32256 + i) * 8;
    const float4 u0 = *(const float4*)up;
    const float4 u1 = *(const float4*)(up + 4);

    float vs[10][4];
#pragma unroll
    for (int j = 0; j < 10; ++j) {
        const float4 t = *(const float4*)(vsum + (b * 10 + j) * 16 + q * 4);
        vs[j][0] = t.x; vs[j][1] = t.y; vs[j][2] = t.z; vs[j][3] = t.w;
    }

    float uhf[10][4], logit[10];
#pragma unroll
    for (int j = 0; j < 10; ++j) {
        const float* wp = W + (((long)j * 32256 + i) * 16 + q * 4) * 8;
        float lg = 0.f;
#pragma unroll
        for (int t = 0; t < 4; ++t) {
            const float4 wa = *(const float4*)(wp + t * 8);
            const float4 wb = *(const float4*)(wp + t * 8 + 4);
            float h = wa.x * u0.x + wa.y * u0.y + wa.z * u0.z + wa.w * u0.w
                    + wb.x * u1.x + wb.y * u1.y + wb.z * u1.z + wb.w * u1.w;
            uhf[j][t] = h;
            lg = fmaf(vs[j][t], h, lg);
        }
        lg += __shfl_xor(lg, 1);   // sum over quad -> full 16-dim dot
        lg += __shfl_xor(lg, 2);
        logit[j] = lg;
    }
    float mx = logit[0];
#pragma unroll
    for (int j = 1; j < 10; ++j) mx = fmaxf(mx, logit[j]);
    float den = 0.f, e[10];
#pragma unroll
    for (int j = 0; j < 10; ++j) { e[j] = __expf(logit[j] - mx); den += e[j]; }
    const float inv = __builtin_amdgcn_rcpf(den);

    // s contribution c_j * uh, reduced over the wave's 16 capsule slots
#pragma unroll
    for (int j = 0; j < 10; ++j) {
        const float c = e[j] * inv;
#pragma unroll
        for (int t = 0; t < 4; ++t) {
            float v2 = c * uhf[j][t];
            v2 += __shfl_xor(v2, 4);
            v2 += __shfl_xor(v2, 8);
            v2 += __shfl_xor(v2, 16);
            v2 += __shfl_xor(v2, 32);
            if (lane < 4) red[wv * 160 + j * 16 + q * 4 + t] = v2;
        }
    }
    __syncthreads();
    // block-level reduce over 4 waves -> one atomic per (j,d) per block
    if (tid < 160) {
        const float s = red[tid] + red[160 + tid] + red[320 + tid] + red[480 + tid];
        atomicAdd(&sp[b * 160 + tid], s);
    }
}

// ---------------------------------------------------------------- v = squash(s); vsum += v
__global__ void k_finish(const float* __restrict__ sp, float* __restrict__ vsum,
                         float* __restrict__ out, const int fin)
{
    const int t = threadIdx.x;
    if (t >= 160) return;          // t = b*10 + j
    const float* s = sp + t * 16;
    float sv[16]; float sq = 0.f;
#pragma unroll
    for (int d = 0; d < 16; ++d) { sv[d] = s[d]; sq += sv[d] * sv[d]; }
    const float sc = sq / ((1.f + sq) * sqrtf(sq + 1e-7f));
    if (fin) {
#pragma unroll
        for (int d = 0; d < 16; ++d) out[t * 16 + d] = sv[d] * sc;
    } else {
        float* vp = vsum + t * 16;
#pragma unroll
        for (int d = 0; d < 16; ++d) vp[d] += sv[d] * sc;
    }
}

extern "C" void kernel_launch(void* const* d_in, const int* in_sizes, int n_in,
                              void* d_out, int out_size, void* d_ws, size_t ws_size,
                              hipStream_t stream)
{
    const float* x   = (const float*)d_in[0];
    const float* c1w = (const float*)d_in[1];
    const float* c1b = (const float*)d_in[2];
    const float* pcw = (const float*)d_in[3];
    const float* pcb = (const float*)d_in[4];
    const float* cW  = (const float*)d_in[5];
    float* out = (float*)d_out;

    char* ws = (char*)d_ws;
    __hip_bfloat16* y  = (__hip_bfloat16*)(ws);                 // 42,205,184 B
    __hip_bfloat16* wt = (__hip_bfloat16*)(ws + 42205184);      // 10,616,832 B
    float* p0   = (float*)(ws + 52822016);                      // 16,515,072 B
    float* p1   = (float*)(ws + 69337088);                      // 16,515,072 B
    float* p2   = (float*)(ws + 85852160);                      // 16,515,072 B
    float* sp   = (float*)(ws + 102367232);                     // 3*2560*4 B
    float* vsum = (float*)(ws + 102397952);                     // 2560*4 B

    // zero s-partials + vsum (ws is poisoned 0xAA before every call)
    hipMemsetAsync(sp, 0, (3 * 2560 + 2560) * 4, stream);

    k_conv1<<<16 * 92, 256, 0, stream>>>(x, c1w, c1b, y);
    k_wt<<<20736, 256, 0, stream>>>(pcw, wt);
    k_pcconv<<<dim3(126, 2, 3), 256, 0, stream>>>(y, wt, p0, p1, p2);
    k_squash<<<2016, 256, 0, stream>>>(p0, p1, p2, pcb, p0);   // u in-place into p0
    for (int it = 0; it < 3; ++it) {
        k_route3<<<dim3(16, 504), 256, 0, stream>>>(p0, cW, vsum, sp + it * 2560);
        k_finish<<<1, 256, 0, stream>>>(sp + it * 2560, vsum, out, it == 2 ? 1 : 0);
    }
}

// Round 4
// 809.788 us; speedup vs baseline: 2.1400x; 2.1400x over previous
//
#include <hip/hip_runtime.h>
#include <hip/hip_bf16.h>
#include <hip/hip_fp16.h>
#include <stdint.h>

typedef __bf16 bf16x8_t __attribute__((ext_vector_type(8)));
typedef float  f32x4_t  __attribute__((ext_vector_type(4)));

#define PLANE_H (16L * 32256 * 32)   // halves per j-group plane (33,030,144 B)

// async global->LDS, 16B per lane. LDS dest must be wave-uniform base + lane*16.
__device__ __forceinline__ void gld_lds16(const void* g, void* l) {
    __builtin_amdgcn_global_load_lds(
        (const __attribute__((address_space(1))) uint32_t*)g,
        (__attribute__((address_space(3))) uint32_t*)l, 16, 0, 0);
}

// ---------------------------------------------------------------- conv1 (fp32 vector)
__global__ __launch_bounds__(256) void k_conv1(
    const float* __restrict__ x, const float* __restrict__ w,
    const float* __restrict__ bias, __hip_bfloat16* __restrict__ y)
{
    const int b  = blockIdx.x / 92;
    const int oh = blockIdx.x % 92;
    const int oc = threadIdx.x;
    float wr[81];
#pragma unroll
    for (int t = 0; t < 81; ++t) wr[t] = w[t * 256 + oc];
    const float bs = bias[oc];
    const float* xb = x + (b * 100 + oh) * 64;
    __hip_bfloat16* yb = y + ((b * 92 + oh) * 56) * 256 + oc;
    for (int owg = 0; owg < 56; owg += 4) {
        float a0 = bs, a1 = bs, a2 = bs, a3 = bs;
#pragma unroll
        for (int kh = 0; kh < 9; ++kh) {
            const float* xr = xb + kh * 64 + owg;
            float xv[12];
#pragma unroll
            for (int t = 0; t < 12; ++t) xv[t] = xr[t];
#pragma unroll
            for (int kw = 0; kw < 9; ++kw) {
                const float wv = wr[kh * 9 + kw];
                a0 = fmaf(xv[kw + 0], wv, a0);
                a1 = fmaf(xv[kw + 1], wv, a1);
                a2 = fmaf(xv[kw + 2], wv, a2);
                a3 = fmaf(xv[kw + 3], wv, a3);
            }
        }
        yb[(owg + 0) * 256] = __float2bfloat16(fmaxf(a0, 0.f));
        yb[(owg + 1) * 256] = __float2bfloat16(fmaxf(a1, 0.f));
        yb[(owg + 2) * 256] = __float2bfloat16(fmaxf(a2, 0.f));
        yb[(owg + 3) * 256] = __float2bfloat16(fmaxf(a3, 0.f));
    }
}

// ---------------------------------------------------------------- pc_w transpose+cast
__global__ __launch_bounds__(256) void k_wt(
    const float* __restrict__ w, __hip_bfloat16* __restrict__ wt)
{
    const int idx = blockIdx.x * 256 + threadIdx.x;
    const int oc  = idx / 20736;
    const int k   = idx - oc * 20736;
    wt[idx] = __float2bfloat16(w[k * 256 + oc]);
}

// ---------------------------------------------------------------- PC conv as MFMA GEMM
__global__ __launch_bounds__(256) void k_pcconv(
    const __hip_bfloat16* __restrict__ y,
    const __hip_bfloat16* __restrict__ wt,
    float* __restrict__ pout0, float* __restrict__ pout1, float* __restrict__ pout2)
{
    __shared__ __hip_bfloat16 lA[128 * 32];
    __shared__ __hip_bfloat16 lB[128 * 32];
    float* __restrict__ p = (blockIdx.z == 0) ? pout0 : (blockIdx.z == 1 ? pout1 : pout2);

    const int tid  = threadIdx.x;
    const int m0   = blockIdx.x * 128;
    const int n0   = blockIdx.y * 128;
    const int kc0  = blockIdx.z * 216;
    const int quad = tid & 3;
    const int trow = tid >> 2;

    int ybase[2];
#pragma unroll
    for (int r = 0; r < 2; ++r) {
        const int m  = m0 + r * 64 + trow;
        const int b  = m / 1008;            // 42*24
        const int rm = m - b * 1008;
        const int oh = rm / 24;
        const int ow = rm - oh * 24;
        ybase[r] = ((b * 92 + 2 * oh) * 56 + 2 * ow) * 256 + quad * 8;
    }
    int wbase[2];
#pragma unroll
    for (int r = 0; r < 2; ++r)
        wbase[r] = (n0 + r * 64 + trow) * 20736 + quad * 8;

    f32x4_t acc[4][4];
#pragma unroll
    for (int mi = 0; mi < 4; ++mi)
#pragma unroll
        for (int ni = 0; ni < 4; ++ni)
            acc[mi][ni] = (f32x4_t){0.f, 0.f, 0.f, 0.f};

    const int wv   = tid >> 6;
    const int lane = tid & 63;
    const int mw   = (wv >> 1) * 64;
    const int nw   = (wv & 1) * 64;
    const int lr   = lane & 15;
    const int lq   = lane >> 4;

    for (int kc = kc0; kc < kc0 + 216; ++kc) {
        const int k0   = kc * 32;
        const int khw  = k0 >> 8;
        const int ic0  = k0 & 255;
        const int kh   = khw / 9;
        const int kw2  = khw - kh * 9;
        const int aoff = (kh * 56 + kw2) * 256 + ic0;
        __syncthreads();
#pragma unroll
        for (int r = 0; r < 2; ++r)
            gld_lds16(y + ybase[r] + aoff, &lA[r * 2048 + tid * 8]);
#pragma unroll
        for (int r = 0; r < 2; ++r)
            gld_lds16(wt + wbase[r] + k0, &lB[r * 2048 + tid * 8]);
        __builtin_amdgcn_s_waitcnt(0);
        __syncthreads();
        bf16x8_t af[4], bfr[4];
#pragma unroll
        for (int mi = 0; mi < 4; ++mi)
            af[mi] = *(const bf16x8_t*)&lA[(mw + mi * 16 + lr) * 32 + lq * 8];
#pragma unroll
        for (int ni = 0; ni < 4; ++ni)
            bfr[ni] = *(const bf16x8_t*)&lB[(nw + ni * 16 + lr) * 32 + lq * 8];
#pragma unroll
        for (int mi = 0; mi < 4; ++mi)
#pragma unroll
            for (int ni = 0; ni < 4; ++ni)
                acc[mi][ni] = __builtin_amdgcn_mfma_f32_16x16x32_bf16(
                    af[mi], bfr[ni], acc[mi][ni], 0, 0, 0);
    }
#pragma unroll
    for (int mi = 0; mi < 4; ++mi)
#pragma unroll
        for (int ni = 0; ni < 4; ++ni) {
            const int col = n0 + nw + ni * 16 + lr;
#pragma unroll
            for (int rr = 0; rr < 4; ++rr) {
                const int row = m0 + mw + mi * 16 + lq * 4 + rr;
                p[row * 256 + col] = acc[mi][ni][rr];
            }
        }
}

// ---------------------------------------------------------------- squash (sums K-splits)
__global__ __launch_bounds__(256) void k_squash(
    const float* p0, const float* p1, const float* p2,
    const float* __restrict__ bias, float* u)
{
    const int g = blockIdx.x * 256 + threadIdx.x;   // < 516096
    const int base = g * 8;
    const int cb = (g & 31) * 8;
    float v[8]; float sq = 0.f;
    const float4 a0 = *(const float4*)(p0 + base), a1 = *(const float4*)(p0 + base + 4);
    const float4 b0 = *(const float4*)(p1 + base), b1 = *(const float4*)(p1 + base + 4);
    const float4 c0 = *(const float4*)(p2 + base), c1 = *(const float4*)(p2 + base + 4);
    v[0] = a0.x + b0.x + c0.x + bias[cb + 0];
    v[1] = a0.y + b0.y + c0.y + bias[cb + 1];
    v[2] = a0.z + b0.z + c0.z + bias[cb + 2];
    v[3] = a0.w + b0.w + c0.w + bias[cb + 3];
    v[4] = a1.x + b1.x + c1.x + bias[cb + 4];
    v[5] = a1.y + b1.y + c1.y + bias[cb + 5];
    v[6] = a1.z + b1.z + c1.z + bias[cb + 6];
    v[7] = a1.w + b1.w + c1.w + bias[cb + 7];
#pragma unroll
    for (int t = 0; t < 8; ++t) sq += v[t] * v[t];
    const float sc = sq / ((1.f + sq) * sqrtf(sq + 1e-7f));
#pragma unroll
    for (int t = 0; t < 8; ++t) u[base + t] = v[t] * sc;
}

// ---------------------------------------------------------------- u_hat precompute (fp16, LDS-staged)
// Plane layout: uh[jg][b][i][q][j2][d] halves, jg = j-group of 2, record per
// (b,i) = 32 halves = 64 B. Block = (b-half, i-chunk of 64); per j-group the
// block assembles an 8b x 64i x 64B tile (32 KB) in LDS, then flushes it with
// dense 16 B/lane stores (4 KB contiguous per b). Kills R2's 4x write amp.
__global__ __launch_bounds__(256) void k_uhat2(
    const float* __restrict__ u, const float* __restrict__ W, __half* __restrict__ uh)
{
    __shared__ __half lbuf[8 * 64 * 32];   // 32 KB
    const int bh  = blockIdx.x;            // 0..2  (b-half)
    const int ic  = blockIdx.y;            // 0..504
    const int tid = threadIdx.x;
    const int q   = tid & 3;               // d-quarter
    const int il  = tid >> 2;              // 0..64
    const int i   = ic * 64 + il;

    for (int jg = 0; jg < 5; ++jg) {
        const float* wb0 = W + ((long)(2 * jg) * 32256 + i) * 128 + q * 32;
        const float* wb1 = wb0 + (long)32256 * 128;
        float4 w0[8], w1[8];
#pragma unroll
        for (int t = 0; t < 8; ++t) w0[t] = *(const float4*)(wb0 + t * 4);
#pragma unroll
        for (int t = 0; t < 8; ++t) w1[t] = *(const float4*)(wb1 + t * 4);
        if (jg) __syncthreads();           // previous flush must finish before rewrite
#pragma unroll
        for (int b = 0; b < 8; ++b) {
            const float* up = u + ((bh * 8 + b) * 32256 + i) * 8;
            const float4 u0 = *(const float4*)up;
            const float4 u1 = *(const float4*)(up + 4);
            union { __half h[8]; uint4 v; } pk;
#pragma unroll
            for (int d = 0; d < 4; ++d) {
                const float4 a = w0[2 * d], c = w0[2 * d + 1];
                pk.h[d] = __float2half(
                    a.x * u0.x + a.y * u0.y + a.z * u0.z + a.w * u0.w +
                    c.x * u1.x + c.y * u1.y + c.z * u1.z + c.w * u1.w);
            }
#pragma unroll
            for (int d = 0; d < 4; ++d) {
                const float4 a = w1[2 * d], c = w1[2 * d + 1];
                pk.h[4 + d] = __float2half(
                    a.x * u0.x + a.y * u0.y + a.z * u0.z + a.w * u0.w +
                    c.x * u1.x + c.y * u1.y + c.z * u1.z + c.w * u1.w);
            }
            *(uint4*)&lbuf[(b * 64 + il) * 32 + q * 8] = pk.v;
        }
        __syncthreads();
        // flush: 8 x 4 KB dense runs
        __half* pb = uh + (long)jg * PLANE_H + ((long)(bh * 8) * 32256 + ic * 64) * 32;
#pragma unroll
        for (int b = 0; b < 8; ++b) {
            const uint4 v = *(const uint4*)&lbuf[b * 2048 + tid * 8];
            *(uint4*)(pb + (long)b * (32256 * 32) + tid * 8) = v;
        }
    }
}

// ---------------------------------------------------------------- routing iteration
// Streams uh planes exactly once (165 MB fp16, zero duplication, dense 16B/lane
// loads). 4 lanes per capsule (lane q owns dims [4q,4q+4)).
__global__ __launch_bounds__(256) void k_route4(
    const __half* __restrict__ uh, const float* __restrict__ vsum,
    float* __restrict__ sp)
{
    __shared__ float red[4 * 160];
    const int b     = blockIdx.x;      // 16
    const int chunk = blockIdx.y;      // 56
    const int tid   = threadIdx.x;
    const int lane  = tid & 63;
    const int wv    = tid >> 6;
    const int q     = lane & 3;
    const int ig    = lane >> 2;

    float vs[10][4];
#pragma unroll
    for (int j = 0; j < 10; ++j) {
        const float4 t = *(const float4*)(vsum + (b * 10 + j) * 16 + q * 4);
        vs[j][0] = t.x; vs[j][1] = t.y; vs[j][2] = t.z; vs[j][3] = t.w;
    }
    float acc[10][4];
#pragma unroll
    for (int j = 0; j < 10; ++j)
#pragma unroll
        for (int t = 0; t < 4; ++t) acc[j][t] = 0.f;

    const int ib = chunk * 576 + wv * 16 + ig;
    for (int ps = 0; ps < 9; ++ps) {
        const int i = ib + ps * 64;
        const long rb = ((long)b * 32256 + i) * 32 + q * 8;
        uint4 r[5];
#pragma unroll
        for (int jg = 0; jg < 5; ++jg)
            r[jg] = *(const uint4*)(uh + jg * PLANE_H + rb);
        float uhf[10][4];
#pragma unroll
        for (int jg = 0; jg < 5; ++jg) {
            const unsigned wd[4] = {r[jg].x, r[jg].y, r[jg].z, r[jg].w};
#pragma unroll
            for (int h2 = 0; h2 < 4; ++h2) {
                const __half2 hh = *(const __half2*)&wd[h2];
                const int j  = jg * 2 + (h2 >> 1);
                const int d0 = (h2 & 1) * 2;
                uhf[j][d0 + 0] = __low2float(hh);
                uhf[j][d0 + 1] = __high2float(hh);
            }
        }
        float logit[10];
#pragma unroll
        for (int j = 0; j < 10; ++j) {
            float lg = vs[j][0] * uhf[j][0] + vs[j][1] * uhf[j][1]
                     + vs[j][2] * uhf[j][2] + vs[j][3] * uhf[j][3];
            lg += __shfl_xor(lg, 1);
            lg += __shfl_xor(lg, 2);
            logit[j] = lg;
        }
        float mx = logit[0];
#pragma unroll
        for (int j = 1; j < 10; ++j) mx = fmaxf(mx, logit[j]);
        float den = 0.f, e[10];
#pragma unroll
        for (int j = 0; j < 10; ++j) { e[j] = __expf(logit[j] - mx); den += e[j]; }
        const float inv = __builtin_amdgcn_rcpf(den);
#pragma unroll
        for (int j = 0; j < 10; ++j) {
            const float c = e[j] * inv;
#pragma unroll
            for (int t = 0; t < 4; ++t) acc[j][t] = fmaf(c, uhf[j][t], acc[j][t]);
        }
    }
    // wave reduce over the 16 capsule slots, then block reduce, one atomic per (j,d)
#pragma unroll
    for (int j = 0; j < 10; ++j)
#pragma unroll
        for (int t = 0; t < 4; ++t) {
            float v2 = acc[j][t];
            v2 += __shfl_xor(v2, 4);
            v2 += __shfl_xor(v2, 8);
            v2 += __shfl_xor(v2, 16);
            v2 += __shfl_xor(v2, 32);
            if (lane < 4) red[wv * 160 + j * 16 + q * 4 + t] = v2;
        }
    __syncthreads();
    if (tid < 160) {
        const float s = red[tid] + red[160 + tid] + red[320 + tid] + red[480 + tid];
        atomicAdd(&sp[b * 160 + tid], s);
    }
}

// ---------------------------------------------------------------- v = squash(s); vsum += v
__global__ void k_finish(const float* __restrict__ sp, float* __restrict__ vsum,
                         float* __restrict__ out, const int fin)
{
    const int t = threadIdx.x;
    if (t >= 160) return;          // t = b*10 + j
    const float* s = sp + t * 16;
    float sv[16]; float sq = 0.f;
#pragma unroll
    for (int d = 0; d < 16; ++d) { sv[d] = s[d]; sq += sv[d] * sv[d]; }
    const float sc = sq / ((1.f + sq) * sqrtf(sq + 1e-7f));
    if (fin) {
#pragma unroll
        for (int d = 0; d < 16; ++d) out[t * 16 + d] = sv[d] * sc;
    } else {
        float* vp = vsum + t * 16;
#pragma unroll
        for (int d = 0; d < 16; ++d) vp[d] += sv[d] * sc;
    }
}

extern "C" void kernel_launch(void* const* d_in, const int* in_sizes, int n_in,
                              void* d_out, int out_size, void* d_ws, size_t ws_size,
                              hipStream_t stream)
{
    const float* x   = (const float*)d_in[0];
    const float* c1w = (const float*)d_in[1];
    const float* c1b = (const float*)d_in[2];
    const float* pcw = (const float*)d_in[3];
    const float* pcb = (const float*)d_in[4];
    const float* cW  = (const float*)d_in[5];
    float* out = (float*)d_out;

    // Workspace: uh overlaps y/wt/p1/p2 (dead after k_squash). Peak 181.7 MB.
    char* ws = (char*)d_ws;
    float* p0 = (float*)(ws);                                   // u lives here after k_squash
    __hip_bfloat16* y  = (__hip_bfloat16*)(ws + 16515072);
    __hip_bfloat16* wt = (__hip_bfloat16*)(ws + 58720256);
    float* p1 = (float*)(ws + 69337088);
    float* p2 = (float*)(ws + 85852160);
    __half* uh = (__half*)(ws + 16515072);                      // 165,150,720 B (5 planes)
    float* sp   = (float*)(ws + 181665792);
    float* vsum = (float*)(ws + 181696512);

    hipMemsetAsync(sp, 0, (3 * 2560 + 2560) * 4, stream);

    k_conv1<<<16 * 92, 256, 0, stream>>>(x, c1w, c1b, y);
    k_wt<<<20736, 256, 0, stream>>>(pcw, wt);
    k_pcconv<<<dim3(126, 2, 3), 256, 0, stream>>>(y, wt, p0, p1, p2);
    k_squash<<<2016, 256, 0, stream>>>(p0, p1, p2, pcb, p0);   // u in-place into p0
    k_uhat2<<<dim3(2, 504), 256, 0, stream>>>(p0, cW, uh);
    for (int it = 0; it < 3; ++it) {
        k_route4<<<dim3(16, 56), 256, 0, stream>>>(uh, vsum, sp + it * 2560);
        k_finish<<<1, 256, 0, stream>>>(sp + it * 2560, vsum, out, it == 2 ? 1 : 0);
    }
}

// Round 5
// 764.643 us; speedup vs baseline: 2.2663x; 1.0590x over previous
//
#include <hip/hip_runtime.h>
#include <hip/hip_bf16.h>
#include <hip/hip_fp16.h>
#include <stdint.h>

typedef __bf16 bf16x8_t __attribute__((ext_vector_type(8)));
typedef float  f32x4_t  __attribute__((ext_vector_type(4)));

#define PLANE_H (16L * 32256 * 32)     // halves per j-group plane
#define PSTRIDE 4128768L               // floats per K-split partial (16,515,072 B)

// async global->LDS, 16B per lane. LDS dest must be wave-uniform base + lane*16.
__device__ __forceinline__ void gld_lds16(const void* g, void* l) {
    __builtin_amdgcn_global_load_lds(
        (const __attribute__((address_space(1))) uint32_t*)g,
        (__attribute__((address_space(3))) uint32_t*)l, 16, 0, 0);
}

// ---------------------------------------------------------------- conv1 (fp32 vector)
__global__ __launch_bounds__(256) void k_conv1(
    const float* __restrict__ x, const float* __restrict__ w,
    const float* __restrict__ bias, __hip_bfloat16* __restrict__ y)
{
    const int b  = blockIdx.x / 92;
    const int oh = blockIdx.x % 92;
    const int oc = threadIdx.x;
    float wr[81];
#pragma unroll
    for (int t = 0; t < 81; ++t) wr[t] = w[t * 256 + oc];
    const float bs = bias[oc];
    const float* xb = x + (b * 100 + oh) * 64;
    __hip_bfloat16* yb = y + ((b * 92 + oh) * 56) * 256 + oc;
    for (int owg = 0; owg < 56; owg += 4) {
        float a0 = bs, a1 = bs, a2 = bs, a3 = bs;
#pragma unroll
        for (int kh = 0; kh < 9; ++kh) {
            const float* xr = xb + kh * 64 + owg;
            float xv[12];
#pragma unroll
            for (int t = 0; t < 12; ++t) xv[t] = xr[t];
#pragma unroll
            for (int kw = 0; kw < 9; ++kw) {
                const float wv = wr[kh * 9 + kw];
                a0 = fmaf(xv[kw + 0], wv, a0);
                a1 = fmaf(xv[kw + 1], wv, a1);
                a2 = fmaf(xv[kw + 2], wv, a2);
                a3 = fmaf(xv[kw + 3], wv, a3);
            }
        }
        yb[(owg + 0) * 256] = __float2bfloat16(fmaxf(a0, 0.f));
        yb[(owg + 1) * 256] = __float2bfloat16(fmaxf(a1, 0.f));
        yb[(owg + 2) * 256] = __float2bfloat16(fmaxf(a2, 0.f));
        yb[(owg + 3) * 256] = __float2bfloat16(fmaxf(a3, 0.f));
    }
}

// ---------------------------------------------------------------- pc_w transpose+cast
__global__ __launch_bounds__(256) void k_wt(
    const float* __restrict__ w, __hip_bfloat16* __restrict__ wt)
{
    const int idx = blockIdx.x * 256 + threadIdx.x;
    const int oc  = idx / 20736;
    const int k   = idx - oc * 20736;
    wt[idx] = __float2bfloat16(w[k * 256 + oc]);
}

// ---------------------------------------------------------------- PC conv as MFMA GEMM
// M=16128, N=256 (full width per block), K=20736, BK=32, K-split x6.
// XCD swizzle: mbx = (bx&7)*16 + (bx>>3) -> 16 consecutive M-blocks per XCD so
// the conv's overlapping y-rows stay in one XCD's L2.
// LDS XOR swizzle: row r's 16B k-chunk c stored at chunk position c^((r>>1)&3)
// -> fragment ds_read_b128 is 2-way bank-aliased (free) instead of 8-way.
__global__ __launch_bounds__(256, 2) void k_pcconv2(
    const __hip_bfloat16* __restrict__ y,
    const __hip_bfloat16* __restrict__ wt,
    float* __restrict__ pbase)
{
    __shared__ __hip_bfloat16 lA[128 * 32];   // 8 KB
    __shared__ __hip_bfloat16 lB[256 * 32];   // 16 KB
    const int mbx = (blockIdx.x & 7) * 16 + (blockIdx.x >> 3);
    if (mbx >= 126) return;
    const int z = blockIdx.y;                 // K-split 0..5
    float* __restrict__ p = pbase + (long)z * PSTRIDE;

    const int tid  = threadIdx.x;
    const int trow = tid >> 2;
    const int quad = tid & 3;
    const int sq   = quad ^ ((trow >> 1) & 3);   // swizzled source chunk

    int ybase[2];
#pragma unroll
    for (int r = 0; r < 2; ++r) {
        const int m  = mbx * 128 + r * 64 + trow;
        const int b  = m / 1008;            // 42*24
        const int rm = m - b * 1008;
        const int oh = rm / 24;
        const int ow = rm - oh * 24;
        ybase[r] = ((b * 92 + 2 * oh) * 56 + 2 * ow) * 256 + sq * 8;
    }
    int wbase[4];
#pragma unroll
    for (int r = 0; r < 4; ++r)
        wbase[r] = (r * 64 + trow) * 20736 + sq * 8;

    f32x4_t acc[4][8];
#pragma unroll
    for (int mi = 0; mi < 4; ++mi)
#pragma unroll
        for (int ni = 0; ni < 8; ++ni)
            acc[mi][ni] = (f32x4_t){0.f, 0.f, 0.f, 0.f};

    const int wv   = tid >> 6;
    const int lane = tid & 63;
    const int mw   = (wv >> 1) * 64;      // wave's M offset (0/64)
    const int nwb  = (wv & 1) * 128;      // wave's N offset (0/128)
    const int lr   = lane & 15;
    const int lq   = lane >> 4;
    const int koff = (lq ^ ((lr >> 1) & 3)) * 8;   // swizzled read chunk

    for (int kc = z * 108; kc < z * 108 + 108; ++kc) {
        const int k0   = kc * 32;
        const int khw  = k0 >> 8;
        const int ic0  = k0 & 255;
        const int kh   = khw / 9;
        const int kw2  = khw - kh * 9;
        const int aoff = (kh * 56 + kw2) * 256 + ic0;
        __syncthreads();
#pragma unroll
        for (int r = 0; r < 2; ++r)
            gld_lds16(y + ybase[r] + aoff, &lA[r * 2048 + tid * 8]);
#pragma unroll
        for (int r = 0; r < 4; ++r)
            gld_lds16(wt + wbase[r] + k0, &lB[r * 2048 + tid * 8]);
        __builtin_amdgcn_s_waitcnt(0);
        __syncthreads();
        bf16x8_t af[4], bfr[8];
#pragma unroll
        for (int mi = 0; mi < 4; ++mi)
            af[mi] = *(const bf16x8_t*)&lA[(mw + mi * 16 + lr) * 32 + koff];
#pragma unroll
        for (int ni = 0; ni < 8; ++ni)
            bfr[ni] = *(const bf16x8_t*)&lB[(nwb + ni * 16 + lr) * 32 + koff];
#pragma unroll
        for (int mi = 0; mi < 4; ++mi)
#pragma unroll
            for (int ni = 0; ni < 8; ++ni)
                acc[mi][ni] = __builtin_amdgcn_mfma_f32_16x16x32_bf16(
                    af[mi], bfr[ni], acc[mi][ni], 0, 0, 0);
    }
#pragma unroll
    for (int mi = 0; mi < 4; ++mi)
#pragma unroll
        for (int ni = 0; ni < 8; ++ni) {
            const int col = nwb + ni * 16 + lr;
#pragma unroll
            for (int rr = 0; rr < 4; ++rr) {
                const int row = mbx * 128 + mw + mi * 16 + lq * 4 + rr;
                p[row * 256 + col] = acc[mi][ni][rr];
            }
        }
}

// ---------------------------------------------------------------- squash (sums 6 K-splits)
__global__ __launch_bounds__(256) void k_squash(
    const float* __restrict__ P, const float* __restrict__ bias, float* u)
{
    const int g = blockIdx.x * 256 + threadIdx.x;   // < 516096
    const int base = g * 8;
    const int cb = (g & 31) * 8;
    float v[8];
#pragma unroll
    for (int t = 0; t < 8; ++t) v[t] = bias[cb + t];
#pragma unroll
    for (int z = 0; z < 6; ++z) {
        const float4 a0 = *(const float4*)(P + z * PSTRIDE + base);
        const float4 a1 = *(const float4*)(P + z * PSTRIDE + base + 4);
        v[0] += a0.x; v[1] += a0.y; v[2] += a0.z; v[3] += a0.w;
        v[4] += a1.x; v[5] += a1.y; v[6] += a1.z; v[7] += a1.w;
    }
    float sq = 0.f;
#pragma unroll
    for (int t = 0; t < 8; ++t) sq += v[t] * v[t];
    const float sc = sq / ((1.f + sq) * sqrtf(sq + 1e-7f));
#pragma unroll
    for (int t = 0; t < 8; ++t) u[base + t] = v[t] * sc;
}

// ---------------------------------------------------------------- u_hat precompute (fp16, LDS-staged)
__global__ __launch_bounds__(256) void k_uhat2(
    const float* __restrict__ u, const float* __restrict__ W, __half* __restrict__ uh)
{
    __shared__ __half lbuf[8 * 64 * 32];   // 32 KB
    const int bh  = blockIdx.x;            // 0..2  (b-half)
    const int ic  = blockIdx.y;            // 0..504
    const int tid = threadIdx.x;
    const int q   = tid & 3;               // d-quarter
    const int il  = tid >> 2;              // 0..64
    const int i   = ic * 64 + il;

    for (int jg = 0; jg < 5; ++jg) {
        const float* wb0 = W + ((long)(2 * jg) * 32256 + i) * 128 + q * 32;
        const float* wb1 = wb0 + (long)32256 * 128;
        float4 w0[8], w1[8];
#pragma unroll
        for (int t = 0; t < 8; ++t) w0[t] = *(const float4*)(wb0 + t * 4);
#pragma unroll
        for (int t = 0; t < 8; ++t) w1[t] = *(const float4*)(wb1 + t * 4);
        if (jg) __syncthreads();           // previous flush must finish before rewrite
#pragma unroll
        for (int b = 0; b < 8; ++b) {
            const float* up = u + ((bh * 8 + b) * 32256 + i) * 8;
            const float4 u0 = *(const float4*)up;
            const float4 u1 = *(const float4*)(up + 4);
            union { __half h[8]; uint4 v; } pk;
#pragma unroll
            for (int d = 0; d < 4; ++d) {
                const float4 a = w0[2 * d], c = w0[2 * d + 1];
                pk.h[d] = __float2half(
                    a.x * u0.x + a.y * u0.y + a.z * u0.z + a.w * u0.w +
                    c.x * u1.x + c.y * u1.y + c.z * u1.z + c.w * u1.w);
            }
#pragma unroll
            for (int d = 0; d < 4; ++d) {
                const float4 a = w1[2 * d], c = w1[2 * d + 1];
                pk.h[4 + d] = __float2half(
                    a.x * u0.x + a.y * u0.y + a.z * u0.z + a.w * u0.w +
                    c.x * u1.x + c.y * u1.y + c.z * u1.z + c.w * u1.w);
            }
            *(uint4*)&lbuf[(b * 64 + il) * 32 + q * 8] = pk.v;
        }
        __syncthreads();
        __half* pb = uh + (long)jg * PLANE_H + ((long)(bh * 8) * 32256 + ic * 64) * 32;
#pragma unroll
        for (int b = 0; b < 8; ++b) {
            const uint4 v = *(const uint4*)&lbuf[b * 2048 + tid * 8];
            *(uint4*)(pb + (long)b * (32256 * 32) + tid * 8) = v;
        }
    }
}

// ---------------------------------------------------------------- routing iteration
__global__ __launch_bounds__(256) void k_route4(
    const __half* __restrict__ uh, const float* __restrict__ vsum,
    float* __restrict__ sp)
{
    __shared__ float red[4 * 160];
    const int b     = blockIdx.x;      // 16
    const int chunk = blockIdx.y;      // 56
    const int tid   = threadIdx.x;
    const int lane  = tid & 63;
    const int wv    = tid >> 6;
    const int q     = lane & 3;
    const int ig    = lane >> 2;

    float vs[10][4];
#pragma unroll
    for (int j = 0; j < 10; ++j) {
        const float4 t = *(const float4*)(vsum + (b * 10 + j) * 16 + q * 4);
        vs[j][0] = t.x; vs[j][1] = t.y; vs[j][2] = t.z; vs[j][3] = t.w;
    }
    float acc[10][4];
#pragma unroll
    for (int j = 0; j < 10; ++j)
#pragma unroll
        for (int t = 0; t < 4; ++t) acc[j][t] = 0.f;

    const int ib = chunk * 576 + wv * 16 + ig;
    for (int ps = 0; ps < 9; ++ps) {
        const int i = ib + ps * 64;
        const long rb = ((long)b * 32256 + i) * 32 + q * 8;
        uint4 r[5];
#pragma unroll
        for (int jg = 0; jg < 5; ++jg)
            r[jg] = *(const uint4*)(uh + jg * PLANE_H + rb);
        float uhf[10][4];
#pragma unroll
        for (int jg = 0; jg < 5; ++jg) {
            const unsigned wd[4] = {r[jg].x, r[jg].y, r[jg].z, r[jg].w};
#pragma unroll
            for (int h2 = 0; h2 < 4; ++h2) {
                const __half2 hh = *(const __half2*)&wd[h2];
                const int j  = jg * 2 + (h2 >> 1);
                const int d0 = (h2 & 1) * 2;
                uhf[j][d0 + 0] = __low2float(hh);
                uhf[j][d0 + 1] = __high2float(hh);
            }
        }
        float logit[10];
#pragma unroll
        for (int j = 0; j < 10; ++j) {
            float lg = vs[j][0] * uhf[j][0] + vs[j][1] * uhf[j][1]
                     + vs[j][2] * uhf[j][2] + vs[j][3] * uhf[j][3];
            lg += __shfl_xor(lg, 1);
            lg += __shfl_xor(lg, 2);
            logit[j] = lg;
        }
        float mx = logit[0];
#pragma unroll
        for (int j = 1; j < 10; ++j) mx = fmaxf(mx, logit[j]);
        float den = 0.f, e[10];
#pragma unroll
        for (int j = 0; j < 10; ++j) { e[j] = __expf(logit[j] - mx); den += e[j]; }
        const float inv = __builtin_amdgcn_rcpf(den);
#pragma unroll
        for (int j = 0; j < 10; ++j) {
            const float c = e[j] * inv;
#pragma unroll
            for (int t = 0; t < 4; ++t) acc[j][t] = fmaf(c, uhf[j][t], acc[j][t]);
        }
    }
#pragma unroll
    for (int j = 0; j < 10; ++j)
#pragma unroll
        for (int t = 0; t < 4; ++t) {
            float v2 = acc[j][t];
            v2 += __shfl_xor(v2, 4);
            v2 += __shfl_xor(v2, 8);
            v2 += __shfl_xor(v2, 16);
            v2 += __shfl_xor(v2, 32);
            if (lane < 4) red[wv * 160 + j * 16 + q * 4 + t] = v2;
        }
    __syncthreads();
    if (tid < 160) {
        const float s = red[tid] + red[160 + tid] + red[320 + tid] + red[480 + tid];
        atomicAdd(&sp[b * 160 + tid], s);
    }
}

// ---------------------------------------------------------------- v = squash(s); vsum += v
__global__ void k_finish(const float* __restrict__ sp, float* __restrict__ vsum,
                         float* __restrict__ out, const int fin)
{
    const int t = threadIdx.x;
    if (t >= 160) return;          // t = b*10 + j
    const float* s = sp + t * 16;
    float sv[16]; float sq = 0.f;
#pragma unroll
    for (int d = 0; d < 16; ++d) { sv[d] = s[d]; sq += sv[d] * sv[d]; }
    const float sc = sq / ((1.f + sq) * sqrtf(sq + 1e-7f));
    if (fin) {
#pragma unroll
        for (int d = 0; d < 16; ++d) out[t * 16 + d] = sv[d] * sc;
    } else {
        float* vp = vsum + t * 16;
#pragma unroll
        for (int d = 0; d < 16; ++d) vp[d] += sv[d] * sc;
    }
}

extern "C" void kernel_launch(void* const* d_in, const int* in_sizes, int n_in,
                              void* d_out, int out_size, void* d_ws, size_t ws_size,
                              hipStream_t stream)
{
    const float* x   = (const float*)d_in[0];
    const float* c1w = (const float*)d_in[1];
    const float* c1b = (const float*)d_in[2];
    const float* pcw = (const float*)d_in[3];
    const float* pcb = (const float*)d_in[4];
    const float* cW  = (const float*)d_in[5];
    float* out = (float*)d_out;

    // Workspace (peak 181,706,752 B):
    //   P (6 K-split partials) [0, 99.1 MB); P[0] becomes u after k_squash.
    //   y [99.1, 141.3), wt [141.3, 151.9)  -- dead after k_pcconv2.
    //   uh [16.5 MB, 181.7 MB)              -- clobbers P[1..5]/y/wt.
    char* ws = (char*)d_ws;
    float* P  = (float*)(ws);                                   // 99,090,432 B
    __hip_bfloat16* y  = (__hip_bfloat16*)(ws + 99090432);      // 42,205,184 B
    __hip_bfloat16* wt = (__hip_bfloat16*)(ws + 141295616);     // 10,616,832 B
    __half* uh = (__half*)(ws + 16515072);                      // 165,150,720 B
    float* sp   = (float*)(ws + 181665792);
    float* vsum = (float*)(ws + 181696512);

    hipMemsetAsync(sp, 0, (3 * 2560 + 2560) * 4, stream);

    k_conv1<<<16 * 92, 256, 0, stream>>>(x, c1w, c1b, y);
    k_wt<<<20736, 256, 0, stream>>>(pcw, wt);
    k_pcconv2<<<dim3(128, 6), 256, 0, stream>>>(y, wt, P);
    k_squash<<<2016, 256, 0, stream>>>(P, pcb, P);   // u in-place into P[0]
    k_uhat2<<<dim3(2, 504), 256, 0, stream>>>(P, cW, uh);
    for (int it = 0; it < 3; ++it) {
        k_route4<<<dim3(16, 56), 256, 0, stream>>>(uh, vsum, sp + it * 2560);
        k_finish<<<1, 256, 0, stream>>>(sp + it * 2560, vsum, out, it == 2 ? 1 : 0);
    }
}

// Round 6
// 709.488 us; speedup vs baseline: 2.4425x; 1.0777x over previous
//
#include <hip/hip_runtime.h>
#include <hip/hip_bf16.h>
#include <hip/hip_fp16.h>
#include <stdint.h>

typedef __bf16 bf16x8_t __attribute__((ext_vector_type(8)));
typedef float  f32x4_t  __attribute__((ext_vector_type(4)));

#define PLANE_H   (16L * 32256 * 32)   // halves per j-group plane (33,030,144 B)
#define PSTRIDE_H 4128768L             // halves per K-split partial (8,257,536 B)

// async global->LDS, 16B per lane. LDS dest must be wave-uniform base + lane*16.
__device__ __forceinline__ void gld_lds16(const void* g, void* l) {
    __builtin_amdgcn_global_load_lds(
        (const __attribute__((address_space(1))) uint32_t*)g,
        (__attribute__((address_space(3))) uint32_t*)l, 16, 0, 0);
}

// ---------------------------------------------------------------- conv1 (fp32 vector)
__global__ __launch_bounds__(256) void k_conv1(
    const float* __restrict__ x, const float* __restrict__ w,
    const float* __restrict__ bias, __hip_bfloat16* __restrict__ y)
{
    const int b  = blockIdx.x / 92;
    const int oh = blockIdx.x % 92;
    const int oc = threadIdx.x;
    float wr[81];
#pragma unroll
    for (int t = 0; t < 81; ++t) wr[t] = w[t * 256 + oc];
    const float bs = bias[oc];
    const float* xb = x + (b * 100 + oh) * 64;
    __hip_bfloat16* yb = y + ((b * 92 + oh) * 56) * 256 + oc;
    for (int owg = 0; owg < 56; owg += 4) {
        float a0 = bs, a1 = bs, a2 = bs, a3 = bs;
#pragma unroll
        for (int kh = 0; kh < 9; ++kh) {
            const float* xr = xb + kh * 64 + owg;
            float xv[12];
#pragma unroll
            for (int t = 0; t < 12; ++t) xv[t] = xr[t];
#pragma unroll
            for (int kw = 0; kw < 9; ++kw) {
                const float wv = wr[kh * 9 + kw];
                a0 = fmaf(xv[kw + 0], wv, a0);
                a1 = fmaf(xv[kw + 1], wv, a1);
                a2 = fmaf(xv[kw + 2], wv, a2);
                a3 = fmaf(xv[kw + 3], wv, a3);
            }
        }
        yb[(owg + 0) * 256] = __float2bfloat16(fmaxf(a0, 0.f));
        yb[(owg + 1) * 256] = __float2bfloat16(fmaxf(a1, 0.f));
        yb[(owg + 2) * 256] = __float2bfloat16(fmaxf(a2, 0.f));
        yb[(owg + 3) * 256] = __float2bfloat16(fmaxf(a3, 0.f));
    }
}

// ---------------------------------------------------------------- pc_w transpose+cast
__global__ __launch_bounds__(256) void k_wt(
    const float* __restrict__ w, __hip_bfloat16* __restrict__ wt)
{
    const int idx = blockIdx.x * 256 + threadIdx.x;
    const int oc  = idx / 20736;
    const int k   = idx - oc * 20736;
    wt[idx] = __float2bfloat16(w[k * 256 + oc]);
}

// ---------------------------------------------------------------- PC conv as MFMA GEMM
// M=16128, N=256, K=20736. Tile 128x128, BK=64, K-split x12 (27 iters), fp16
// partials. 4 waves of 64x64 -> acc 64 AGPR, regs <=128/wave -> 4 blocks/CU.
// XOR swizzle: LDS[r][p] holds global chunk p^(r&7) -> reads bank-balanced.
// Per-block K-phase stagger breaks barrier phase-lock between resident blocks.
__global__ __launch_bounds__(256, 4) void k_pcconv3(
    const __hip_bfloat16* __restrict__ y,
    const __hip_bfloat16* __restrict__ wt,
    __half* __restrict__ pbase)
{
    __shared__ __hip_bfloat16 lA[128 * 64];   // 16 KB
    __shared__ __hip_bfloat16 lB[128 * 64];   // 16 KB
    const int gx  = blockIdx.x;               // 0..255
    const int nb  = gx & 1;
    const int tm  = gx >> 1;                  // 0..127
    const int mbx = (tm & 7) * 16 + (tm >> 3);
    if (mbx >= 126) return;
    const int z = blockIdx.y;                 // 0..11
    __half* __restrict__ p = pbase + (long)z * PSTRIDE_H;

    const int tid  = threadIdx.x;
    const int lane = tid & 63;
    const int w    = tid >> 6;                // 0..3
    const int oct  = lane >> 3;               // 0..7: row within slab
    const int c    = (lane & 7) ^ oct;        // swizzled source chunk (same all j)

    // staging addresses: wave w covers slabs w*4+j (8 rows each)
    int ybaseA[4], wbB[4];
#pragma unroll
    for (int j = 0; j < 4; ++j) {
        const int r  = w * 32 + j * 8 + oct;        // LDS row 0..127
        const int m  = mbx * 128 + r;
        const int b  = m / 1008;                    // 42*24
        const int rm = m - b * 1008;
        const int oh = rm / 24;
        const int ow = rm - oh * 24;
        ybaseA[j] = ((b * 92 + 2 * oh) * 56 + 2 * ow) * 256 + c * 8;
        wbB[j]    = (nb * 128 + r) * 20736 + c * 8;
    }

    f32x4_t acc[4][4];
#pragma unroll
    for (int mi = 0; mi < 4; ++mi)
#pragma unroll
        for (int ni = 0; ni < 4; ++ni)
            acc[mi][ni] = (f32x4_t){0.f, 0.f, 0.f, 0.f};

    const int mw = (w >> 1) * 64;
    const int nw = (w & 1) * 64;
    const int lr = lane & 15;
    const int lq = lane >> 4;
    const int koff0 = ((lq + 0) ^ (lr & 7)) * 8;
    const int koff1 = ((lq + 4) ^ (lr & 7)) * 8;

    const int off = (gx * 11 + z * 5) % 27;
    for (int it = 0; it < 27; ++it) {
        const int kc   = z * 27 + ((it + off) % 27);
        const int k0   = kc * 64;                 // 64 | 256 -> never crosses (kh,kw)
        const int khw  = k0 >> 8;
        const int ic0  = k0 & 255;
        const int kh   = khw / 9;
        const int kw2  = khw - kh * 9;
        const int aoff = (kh * 56 + kw2) * 256 + ic0;
        __syncthreads();
#pragma unroll
        for (int j = 0; j < 4; ++j)
            gld_lds16(y + ybaseA[j] + aoff, &lA[(w * 32 + j * 8) * 64 + lane * 8]);
#pragma unroll
        for (int j = 0; j < 4; ++j)
            gld_lds16(wt + wbB[j] + k0, &lB[(w * 32 + j * 8) * 64 + lane * 8]);
        __builtin_amdgcn_s_waitcnt(0);
        __syncthreads();
#pragma unroll
        for (int t = 0; t < 2; ++t) {
            const int koff = t ? koff1 : koff0;
            bf16x8_t af[4], bfr[4];
#pragma unroll
            for (int mi = 0; mi < 4; ++mi)
                af[mi] = *(const bf16x8_t*)&lA[(mw + mi * 16 + lr) * 64 + koff];
#pragma unroll
            for (int ni = 0; ni < 4; ++ni)
                bfr[ni] = *(const bf16x8_t*)&lB[(nw + ni * 16 + lr) * 64 + koff];
#pragma unroll
            for (int mi = 0; mi < 4; ++mi)
#pragma unroll
                for (int ni = 0; ni < 4; ++ni)
                    acc[mi][ni] = __builtin_amdgcn_mfma_f32_16x16x32_bf16(
                        af[mi], bfr[ni], acc[mi][ni], 0, 0, 0);
        }
    }
#pragma unroll
    for (int mi = 0; mi < 4; ++mi)
#pragma unroll
        for (int ni = 0; ni < 4; ++ni) {
            const int col = nb * 128 + nw + ni * 16 + lr;
#pragma unroll
            for (int rr = 0; rr < 4; ++rr) {
                const int row = mbx * 128 + mw + mi * 16 + lq * 4 + rr;
                p[(long)row * 256 + col] = __float2half(acc[mi][ni][rr]);
            }
        }
}

// ---------------------------------------------------------------- squash (sums 12 fp16 K-splits)
__global__ __launch_bounds__(256) void k_squash(
    const __half* __restrict__ Ph, const float* __restrict__ bias, float* __restrict__ u)
{
    const int g = blockIdx.x * 256 + threadIdx.x;   // < 516096
    const long base = (long)g * 8;
    const int cb = (g & 31) * 8;
    float v[8];
#pragma unroll
    for (int t = 0; t < 8; ++t) v[t] = bias[cb + t];
#pragma unroll
    for (int z = 0; z < 12; ++z) {
        const uint4 r = *(const uint4*)(Ph + z * PSTRIDE_H + base);
        const unsigned wd[4] = {r.x, r.y, r.z, r.w};
#pragma unroll
        for (int h2 = 0; h2 < 4; ++h2) {
            const __half2 hh = *(const __half2*)&wd[h2];
            v[h2 * 2 + 0] += __low2float(hh);
            v[h2 * 2 + 1] += __high2float(hh);
        }
    }
    float sq = 0.f;
#pragma unroll
    for (int t = 0; t < 8; ++t) sq += v[t] * v[t];
    const float sc = sq / ((1.f + sq) * sqrtf(sq + 1e-7f));
#pragma unroll
    for (int t = 0; t < 8; ++t) u[base + t] = v[t] * sc;
}

// ---------------------------------------------------------------- u_hat precompute + fused iter-0 s
// Iter 0: b=0 -> softmax c = exactly 0.1 -> s0[b,j,d] = 0.1*sum_i uh[b,i,j,d].
// Accumulated via in-wave shuffle + LDS + one atomic per (b,j,d) slot per block.
__global__ __launch_bounds__(256) void k_uhat2(
    const float* __restrict__ u, const float* __restrict__ W, __half* __restrict__ uh,
    float* __restrict__ sp0)
{
    __shared__ __half lbuf[8 * 64 * 32];   // 32 KB
    __shared__ float red[4 * 256];         // 4 KB
    const int bh   = blockIdx.x;           // 0..2  (b-half)
    const int ic   = blockIdx.y;           // 0..504
    const int tid  = threadIdx.x;
    const int lane = tid & 63;
    const int wv   = tid >> 6;
    const int q    = tid & 3;              // d-quarter
    const int il   = tid >> 2;             // 0..64
    const int i    = ic * 64 + il;

    for (int jg = 0; jg < 5; ++jg) {
        const float* wb0 = W + ((long)(2 * jg) * 32256 + i) * 128 + q * 32;
        const float* wb1 = wb0 + (long)32256 * 128;
        float4 w0[8], w1[8];
#pragma unroll
        for (int t = 0; t < 8; ++t) w0[t] = *(const float4*)(wb0 + t * 4);
#pragma unroll
        for (int t = 0; t < 8; ++t) w1[t] = *(const float4*)(wb1 + t * 4);
        if (jg) __syncthreads();           // previous flush/reduce must finish
#pragma unroll
        for (int b = 0; b < 8; ++b) {
            const float* up = u + ((bh * 8 + b) * 32256 + i) * 8;
            const float4 u0 = *(const float4*)up;
            const float4 u1 = *(const float4*)(up + 4);
            union { __half h[8]; uint4 v; } pk;
#pragma unroll
            for (int d = 0; d < 4; ++d) {
                const float4 a = w0[2 * d], cc = w0[2 * d + 1];
                pk.h[d] = __float2half(
                    a.x * u0.x + a.y * u0.y + a.z * u0.z + a.w * u0.w +
                    cc.x * u1.x + cc.y * u1.y + cc.z * u1.z + cc.w * u1.w);
            }
#pragma unroll
            for (int d = 0; d < 4; ++d) {
                const float4 a = w1[2 * d], cc = w1[2 * d + 1];
                pk.h[4 + d] = __float2half(
                    a.x * u0.x + a.y * u0.y + a.z * u0.z + a.w * u0.w +
                    cc.x * u1.x + cc.y * u1.y + cc.z * u1.z + cc.w * u1.w);
            }
            *(uint4*)&lbuf[(b * 64 + il) * 32 + q * 8] = pk.v;
            // fused iter-0 s: reduce over the wave's 16 i-slots (lane strides 4..32)
            float rv[8];
#pragma unroll
            for (int t = 0; t < 8; ++t) rv[t] = __half2float(pk.h[t]);
#pragma unroll
            for (int t = 0; t < 8; ++t) {
                rv[t] += __shfl_xor(rv[t], 4);
                rv[t] += __shfl_xor(rv[t], 8);
                rv[t] += __shfl_xor(rv[t], 16);
                rv[t] += __shfl_xor(rv[t], 32);
            }
            if (lane < 4) {                // lane == q for these threads
#pragma unroll
                for (int t = 0; t < 8; ++t)
                    red[wv * 256 + b * 32 + (t >> 2) * 16 + q * 4 + (t & 3)] = rv[t];
            }
        }
        __syncthreads();
        // flush uh tile: 8 x 4 KB dense runs
        __half* pb = uh + (long)jg * PLANE_H + ((long)(bh * 8) * 32256 + ic * 64) * 32;
#pragma unroll
        for (int b = 0; b < 8; ++b) {
            const uint4 v = *(const uint4*)&lbuf[b * 2048 + tid * 8];
            *(uint4*)(pb + (long)b * (32256 * 32) + tid * 8) = v;
        }
        // block-reduce s0 partials: slot = b*32 + j2*16 + q*4 + d
        {
            const float v = red[tid] + red[256 + tid] + red[512 + tid] + red[768 + tid];
            const int bb = tid >> 5, j2 = (tid >> 4) & 1, dd = tid & 15;
            atomicAdd(&sp0[((bh * 8 + bb) * 10 + (2 * jg + j2)) * 16 + dd], 0.1f * v);
        }
    }
}

// ---------------------------------------------------------------- routing iteration
__global__ __launch_bounds__(256) void k_route4(
    const __half* __restrict__ uh, const float* __restrict__ vsum,
    float* __restrict__ sp)
{
    __shared__ float red[4 * 160];
    const int b     = blockIdx.x;      // 16
    const int chunk = blockIdx.y;      // 56
    const int tid   = threadIdx.x;
    const int lane  = tid & 63;
    const int wv    = tid >> 6;
    const int q     = lane & 3;
    const int ig    = lane >> 2;

    float vs[10][4];
#pragma unroll
    for (int j = 0; j < 10; ++j) {
        const float4 t = *(const float4*)(vsum + (b * 10 + j) * 16 + q * 4);
        vs[j][0] = t.x; vs[j][1] = t.y; vs[j][2] = t.z; vs[j][3] = t.w;
    }
    float acc[10][4];
#pragma unroll
    for (int j = 0; j < 10; ++j)
#pragma unroll
        for (int t = 0; t < 4; ++t) acc[j][t] = 0.f;

    const int ib = chunk * 576 + wv * 16 + ig;
    for (int ps = 0; ps < 9; ++ps) {
        const int i = ib + ps * 64;
        const long rb = ((long)b * 32256 + i) * 32 + q * 8;
        uint4 r[5];
#pragma unroll
        for (int jg = 0; jg < 5; ++jg)
            r[jg] = *(const uint4*)(uh + jg * PLANE_H + rb);
        float uhf[10][4];
#pragma unroll
        for (int jg = 0; jg < 5; ++jg) {
            const unsigned wd[4] = {r[jg].x, r[jg].y, r[jg].z, r[jg].w};
#pragma unroll
            for (int h2 = 0; h2 < 4; ++h2) {
                const __half2 hh = *(const __half2*)&wd[h2];
                const int j  = jg * 2 + (h2 >> 1);
                const int d0 = (h2 & 1) * 2;
                uhf[j][d0 + 0] = __low2float(hh);
                uhf[j][d0 + 1] = __high2float(hh);
            }
        }
        float logit[10];
#pragma unroll
        for (int j = 0; j < 10; ++j) {
            float lg = vs[j][0] * uhf[j][0] + vs[j][1] * uhf[j][1]
                     + vs[j][2] * uhf[j][2] + vs[j][3] * uhf[j][3];
            lg += __shfl_xor(lg, 1);
            lg += __shfl_xor(lg, 2);
            logit[j] = lg;
        }
        float mx = logit[0];
#pragma unroll
        for (int j = 1; j < 10; ++j) mx = fmaxf(mx, logit[j]);
        float den = 0.f, e[10];
#pragma unroll
        for (int j = 0; j < 10; ++j) { e[j] = __expf(logit[j] - mx); den += e[j]; }
        const float inv = __builtin_amdgcn_rcpf(den);
#pragma unroll
        for (int j = 0; j < 10; ++j) {
            const float c = e[j] * inv;
#pragma unroll
            for (int t = 0; t < 4; ++t) acc[j][t] = fmaf(c, uhf[j][t], acc[j][t]);
        }
    }
#pragma unroll
    for (int j = 0; j < 10; ++j)
#pragma unroll
        for (int t = 0; t < 4; ++t) {
            float v2 = acc[j][t];
            v2 += __shfl_xor(v2, 4);
            v2 += __shfl_xor(v2, 8);
            v2 += __shfl_xor(v2, 16);
            v2 += __shfl_xor(v2, 32);
            if (lane < 4) red[wv * 160 + j * 16 + q * 4 + t] = v2;
        }
    __syncthreads();
    if (tid < 160) {
        const float s = red[tid] + red[160 + tid] + red[320 + tid] + red[480 + tid];
        atomicAdd(&sp[b * 160 + tid], s);
    }
}

// ---------------------------------------------------------------- v = squash(s); vsum += v
__global__ void k_finish(const float* __restrict__ sp, float* __restrict__ vsum,
                         float* __restrict__ out, const int fin)
{
    const int t = threadIdx.x;
    if (t >= 160) return;          // t = b*10 + j
    const float* s = sp + t * 16;
    float sv[16]; float sq = 0.f;
#pragma unroll
    for (int d = 0; d < 16; ++d) { sv[d] = s[d]; sq += sv[d] * sv[d]; }
    const float sc = sq / ((1.f + sq) * sqrtf(sq + 1e-7f));
    if (fin) {
#pragma unroll
        for (int d = 0; d < 16; ++d) out[t * 16 + d] = sv[d] * sc;
    } else {
        float* vp = vsum + t * 16;
#pragma unroll
        for (int d = 0; d < 16; ++d) vp[d] += sv[d] * sc;
    }
}

extern "C" void kernel_launch(void* const* d_in, const int* in_sizes, int n_in,
                              void* d_out, int out_size, void* d_ws, size_t ws_size,
                              hipStream_t stream)
{
    const float* x   = (const float*)d_in[0];
    const float* c1w = (const float*)d_in[1];
    const float* c1b = (const float*)d_in[2];
    const float* pcw = (const float*)d_in[3];
    const float* pcb = (const float*)d_in[4];
    const float* cW  = (const float*)d_in[5];
    float* out = (float*)d_out;

    // Workspace (peak 181,706,752 B — same as proven R4/R5 layout):
    //   u  [0, 16.5 MB)                          fp32, written by k_squash
    //   Ph [16.5, 115.6)   12 fp16 K-partials    dead after k_squash
    //   y  [115.6, 157.8)  bf16 conv1 out        dead after k_pcconv3
    //   wt [157.8, 168.4)  bf16 transposed pc_w  dead after k_pcconv3
    //   uh [16.5, 181.7)   fp16 u_hat planes     clobbers Ph/y/wt
    char* ws = (char*)d_ws;
    float* u  = (float*)(ws);                                   // 16,515,072 B
    __half* Ph = (__half*)(ws + 16515072);                      // 99,090,432 B
    __hip_bfloat16* y  = (__hip_bfloat16*)(ws + 115605504);     // 42,205,184 B
    __hip_bfloat16* wt = (__hip_bfloat16*)(ws + 157810688);     // 10,616,832 B
    __half* uh = (__half*)(ws + 16515072);                      // 165,150,720 B
    float* sp   = (float*)(ws + 181665792);                     // 3*2560*4 B
    float* vsum = (float*)(ws + 181696512);                     // 2560*4 B

    hipMemsetAsync(sp, 0, (3 * 2560 + 2560) * 4, stream);

    k_conv1<<<16 * 92, 256, 0, stream>>>(x, c1w, c1b, y);
    k_wt<<<20736, 256, 0, stream>>>(pcw, wt);
    k_pcconv3<<<dim3(256, 12), 256, 0, stream>>>(y, wt, Ph);
    k_squash<<<2016, 256, 0, stream>>>(Ph, pcb, u);
    k_uhat2<<<dim3(2, 504), 256, 0, stream>>>(u, cW, uh, sp);     // fused iter-0 s
    k_finish<<<1, 256, 0, stream>>>(sp, vsum, out, 0);            // v0 -> vsum
    k_route4<<<dim3(16, 56), 256, 0, stream>>>(uh, vsum, sp + 2560);
    k_finish<<<1, 256, 0, stream>>>(sp + 2560, vsum, out, 0);     // v1 -> vsum
    k_route4<<<dim3(16, 56), 256, 0, stream>>>(uh, vsum, sp + 5120);
    k_finish<<<1, 256, 0, stream>>>(sp + 5120, vsum, out, 1);     // v2 -> out
}